// Round 8
// baseline (216.749 us; speedup 1.0000x reference)
//
#include <hip/hip_runtime.h>

// PartChamferLoss: src/dst [B=16, K=8, 3, 1024] f32 -> scalar f32.
// R8: compute the d2 matrix ONCE (shared cross terms), reduce both directions
// simultaneously. K1: block = (bk, 128-row band) x 1024 cols; thread = 8 rows
// x 64 cols; inner: 3 pk_fma + v_min3 + pk_add + 2 min per 2 elements.
// Row-mins complete in-block (plain rowsum store); col-mins via in-wave
// shuffle reduce + global uint atomicMin (memset-0xFF init). K2: single block
// reduces rowsums + colmins -> out[0] plain store.

typedef float v2f __attribute__((ext_vector_type(2)));

#define NPTS 1024
#define ROWS 128   // rows per block (band)
#define TPB 256
#define RM 8       // rows per thread
#define NCHUNK 4
#define QPC 8      // col-pair steps per chunk -> 64 cols per thread

__device__ __forceinline__ v2f pk_fma(v2f a, v2f b, v2f c) {
  v2f d;
  asm("v_pk_fma_f32 %0, %1, %2, %3" : "=v"(d) : "v"(a), "v"(b), "v"(c));
  return d;
}
__device__ __forceinline__ float min3f(float a, float b, float c) {
  float d;
  asm("v_min3_f32 %0, %1, %2, %3" : "=v"(d) : "v"(a), "v"(b), "v"(c));
  return d;
}

__global__ __launch_bounds__(TPB, 4) void chamfer_tile_kernel(
    const float* __restrict__ src, const float* __restrict__ dst,
    unsigned* __restrict__ colmin,  // [BK*NPTS] uint-ordered clamped d2 mins
    float* __restrict__ rowsum,     // [BK*8] per-block row sqrt-sums
    int BK) {
  __shared__ float4 rowq[ROWS];      // {-2x, -2y, -2z, sq}
  __shared__ float4 colqA[NPTS / 2]; // {x0, x1, y0, y1}  (SoA pair split ->
  __shared__ float4 colqB[NPTS / 2]; // {z0, z1, s0, s1}   2-way banks, free)
  __shared__ float wred[4];

  const int t = threadIdx.x;
  const int bk = blockIdx.x >> 3;
  const int rb = blockIdx.x & 7;
  const float* S = src + (size_t)bk * 3 * NPTS;
  const float* D = dst + (size_t)bk * 3 * NPTS;

  // Stage the band's 128 row (src) coefficient quads.
  if (t < ROWS) {
    int m = rb * ROWS + t;
    float x = S[m], y = S[NPTS + m], z = S[2 * NPTS + m];
    rowq[t] = make_float4(-2.f * x, -2.f * y, -2.f * z,
                          fmaf(x, x, fmaf(y, y, z * z)));
  }
  // Stage all 1024 col (dst) points as 512 SoA pairs.
  for (int p = t; p < NPTS / 2; p += TPB) {
    float x0 = D[2 * p],            x1 = D[2 * p + 1];
    float y0 = D[NPTS + 2 * p],     y1 = D[NPTS + 2 * p + 1];
    float z0 = D[2 * NPTS + 2 * p], z1 = D[2 * NPTS + 2 * p + 1];
    colqA[p] = make_float4(x0, x1, y0, y1);
    colqB[p] = make_float4(z0, z1, fmaf(x0, x0, fmaf(y0, y0, z0 * z0)),
                                   fmaf(x1, x1, fmaf(y1, y1, z1 * z1)));
  }
  __syncthreads();

  const int c = t & 15;   // col-group (16)
  const int r = t >> 4;   // row-group (16): rows r*8 .. r*8+7

  // Row coefficients pre-broadcast into v2f pairs (prologue-only movs).
  v2f rxp[RM], ryp[RM], rzp[RM], sqp[RM];
  float rmn[RM];
#pragma unroll
  for (int i = 0; i < RM; ++i) {
    float4 q = rowq[r * RM + i];
    rxp[i] = (v2f){q.x, q.x};
    ryp[i] = (v2f){q.y, q.y};
    rzp[i] = (v2f){q.z, q.z};
    sqp[i] = (v2f){q.w, q.w};
    rmn[i] = 3.4e38f;
  }

  for (int k = 0; k < NCHUNK; ++k) {
    v2f cm[QPC];
#pragma unroll
    for (int q = 0; q < QPC; ++q) cm[q] = (v2f){3.4e38f, 3.4e38f};

#pragma unroll
    for (int q = 0; q < QPC; ++q) {
      const int P = k * 128 + q * 16 + c;
      float4 A = colqA[P];  // 16 consecutive quads across c -> 2-way banks
      float4 B = colqB[P];
      v2f xx = {A.x, A.y}, yy = {A.z, A.w};
      v2f zz = {B.x, B.y}, ss = {B.z, B.w};
#pragma unroll
      for (int i = 0; i < RM; ++i) {
        v2f v = pk_fma(rzp[i], zz, ss);      // sq_n - 2*dot, 2 cols at once
        v = pk_fma(ryp[i], yy, v);
        v = pk_fma(rxp[i], xx, v);
        rmn[i] = min3f(rmn[i], v.x, v.y);    // row-min (fwd), 1 inst/2 elts
        v2f cv = v + sqp[i];                 // full d2 for col-min (bwd)
        cm[q].x = fminf(cm[q].x, cv.x);
        cm[q].y = fminf(cm[q].y, cv.y);
      }
    }
    // Col-min flush: reduce across the wave's 4 row-lanes, then one
    // fire-and-forget global atomicMin per col from the surviving lanes.
#pragma unroll
    for (int q = 0; q < QPC; ++q) {
      float a = cm[q].x, b = cm[q].y;
      a = fminf(a, __shfl_xor(a, 16)); a = fminf(a, __shfl_xor(a, 32));
      b = fminf(b, __shfl_xor(b, 16)); b = fminf(b, __shfl_xor(b, 32));
      if (((t >> 4) & 3) == 0) {
        const int P = k * 128 + q * 16 + c;
        atomicMin(&colmin[bk * NPTS + 2 * P],
                  __float_as_uint(fmaxf(a, 0.f)));
        atomicMin(&colmin[bk * NPTS + 2 * P + 1],
                  __float_as_uint(fmaxf(b, 0.f)));
      }
    }
  }

  // Row finish: butterfly-min across the 16 col-lanes, add sq_m, sqrt, sum.
  float rsum = 0.f;
#pragma unroll
  for (int i = 0; i < RM; ++i) {
    float a = rmn[i];
    a = fminf(a, __shfl_xor(a, 1));
    a = fminf(a, __shfl_xor(a, 2));
    a = fminf(a, __shfl_xor(a, 4));
    a = fminf(a, __shfl_xor(a, 8));
    rsum += sqrtf(fmaxf(sqp[i].x + a, 0.f));
  }
  // All 16 c-lanes hold duplicates; count c==0 only, sum the wave, then block.
  float v = (c == 0) ? rsum : 0.f;
  for (int off = 32; off; off >>= 1) v += __shfl_down(v, off);
  if ((t & 63) == 0) wred[t >> 6] = v;
  __syncthreads();
  if (t == 0) rowsum[blockIdx.x] = wred[0] + wred[1] + wred[2] + wred[3];
}

__global__ __launch_bounds__(1024) void chamfer_reduce_kernel(
    const unsigned* __restrict__ colmin, const float* __restrict__ rowsum,
    float* __restrict__ out, int BK, float scale) {
  const int t = threadIdx.x;
  float s = rowsum[t];  // exactly BK*8 = 1024 entries
  const int CN = BK * NPTS;
  for (int j = t; j < CN; j += 1024)
    s += sqrtf(__uint_as_float(colmin[j]));  // already clamped >= 0
  for (int off = 32; off; off >>= 1) s += __shfl_down(s, off);
  __shared__ float wr[16];
  if ((t & 63) == 0) wr[t >> 6] = s;
  __syncthreads();
  if (t == 0) {
    float tot = 0.f;
#pragma unroll
    for (int w = 0; w < 16; ++w) tot += wr[w];
    out[0] = tot * scale;
  }
}

extern "C" void kernel_launch(void* const* d_in, const int* in_sizes, int n_in,
                              void* d_out, int out_size, void* d_ws, size_t ws_size,
                              hipStream_t stream) {
  const float* src = (const float*)d_in[0];  // [B,K,3,M]
  const float* dst = (const float*)d_in[1];  // [B,K,3,N]
  float* out = (float*)d_out;                // scalar f32

  const int BK = in_sizes[0] / (3 * NPTS);        // 16*8 = 128
  const float scale = 1.0f / (float)(BK * NPTS);  // 1/(B*K*M), M==N

  unsigned* colmin = (unsigned*)d_ws;                       // 512 KB
  float* rowsum = (float*)((char*)d_ws + (size_t)BK * NPTS * 4);

  // Init colmin to 0xFFFFFFFF (> any float bit pattern under uint ordering).
  hipMemsetAsync(colmin, 0xFF, (size_t)BK * NPTS * 4, stream);

  dim3 grid1(BK * 8);  // 1024 blocks of 256 threads (4 blocks/CU)
  chamfer_tile_kernel<<<grid1, TPB, 0, stream>>>(src, dst, colmin, rowsum, BK);

  chamfer_reduce_kernel<<<1, 1024, 0, stream>>>(colmin, rowsum, out, BK, scale);
}

// Round 9
// 82.354 us; speedup vs baseline: 2.6319x; 2.6319x over previous
//
#include <hip/hip_runtime.h>

// PartChamferLoss: src/dst [B=16, K=8, 3, 1024] f32 -> scalar f32.
// R9: shared-d2 (each distance computed ONCE), all reductions ON-CHIP.
// R8 lesson: global atomics = ~128B uncached HBM RMW each (537 MB observed);
// col-min combining now uses wave shfl + LDS atomicMin only.
// K1: block = (bk, row-half): 1024 thr own 512 rows x 1024 cols.
//     Inner 2x2 micro-tile: 6 pk_fma + 2 min3 + 2 pk_add + 2 min3 = 3.0 inst/elt.
//     Row-mins complete -> scalar store. Col partial mins -> 1024-float store.
// K2: 128 blocks merge the 2 half-partials per bk, sqrt, atomicAdd -> ws acc
//     (initialized by K1 block 0; stream order guarantees visibility).
// K3: 1 thread scales acc into out[0].

typedef float v2f __attribute__((ext_vector_type(2)));

#define NPTS 1024
#define TPB 1024
#define RM 8       // rows per thread (2-row pairs)
#define NCHUNK 4
#define QPC 8      // col-pair steps per chunk -> 64 cols per thread

__device__ __forceinline__ v2f pk_fma(v2f a, v2f b, v2f c) {
  v2f d;
  asm("v_pk_fma_f32 %0, %1, %2, %3" : "=v"(d) : "v"(a), "v"(b), "v"(c));
  return d;
}
__device__ __forceinline__ float min3f(float a, float b, float c) {
  float d;
  asm("v_min3_f32 %0, %1, %2, %3" : "=v"(d) : "v"(a), "v"(b), "v"(c));
  return d;
}

__global__ __launch_bounds__(TPB) void chamfer_half_kernel(
    const float* __restrict__ src, const float* __restrict__ dst,
    float* __restrict__ ws,  // [0]=acc, [64..64+2BK)=rowpart, [1024..)=colpart
    int BK) {
  __shared__ float4 rowq[NPTS / 2];   // {-2x,-2y,-2z,sq} for this half's rows
  __shared__ float4 colqA[NPTS / 2];  // {x0,x1,y0,y1}  SoA pair split
  __shared__ float4 colqB[NPTS / 2];  // {z0,z1,s0,s1}
  __shared__ unsigned cmb[NPTS];      // col-min combine (uint-ordered)
  __shared__ float wred[16];

  const int t = threadIdx.x;
  const int bk = blockIdx.x >> 1;
  const int half = blockIdx.x & 1;
  const float* S = src + (size_t)bk * 3 * NPTS;
  const float* D = dst + (size_t)bk * 3 * NPTS;

  if (blockIdx.x == 0 && t == 0) ws[0] = 0.0f;  // init K2's accumulator

  cmb[t] = 0x7F800000u;  // +inf
  if (t < NPTS / 2) {    // stage this half's 512 row quads
    int m = half * (NPTS / 2) + t;
    float x = S[m], y = S[NPTS + m], z = S[2 * NPTS + m];
    rowq[t] = make_float4(-2.f * x, -2.f * y, -2.f * z,
                          fmaf(x, x, fmaf(y, y, z * z)));
  } else {               // stage all 1024 cols as 512 SoA pairs
    int p = t - NPTS / 2;
    const float2* D2 = (const float2*)D;
    float2 xy = D2[p];                     // x0,x1
    float2 yy = D2[NPTS / 2 + p];          // y0,y1
    float2 zz = D2[NPTS + p];              // z0,z1
    colqA[p] = make_float4(xy.x, xy.y, yy.x, yy.y);
    colqB[p] = make_float4(zz.x, zz.y,
                           fmaf(xy.x, xy.x, fmaf(yy.x, yy.x, zz.x * zz.x)),
                           fmaf(xy.y, xy.y, fmaf(yy.y, yy.y, zz.y * zz.y)));
  }
  __syncthreads();

  const int c = t & 15;   // col-group (16): pairs q*16 + c
  const int r = t >> 4;   // row-group (64): rows r*8 .. r*8+7

  v2f rxp[RM], ryp[RM], rzp[RM], sqp[RM];
  float rmn[RM];
#pragma unroll
  for (int i = 0; i < RM; ++i) {
    float4 q = rowq[r * RM + i];
    rxp[i] = (v2f){q.x, q.x};
    ryp[i] = (v2f){q.y, q.y};
    rzp[i] = (v2f){q.z, q.z};
    sqp[i] = (v2f){q.w, q.w};
    rmn[i] = 3.4e38f;
  }

  for (int k = 0; k < NCHUNK; ++k) {
    v2f cm[QPC];
#pragma unroll
    for (int q = 0; q < QPC; ++q) cm[q] = (v2f){3.4e38f, 3.4e38f};

#pragma unroll
    for (int q = 0; q < QPC; ++q) {
      const int P = k * 128 + q * 16 + c;
      float4 A = colqA[P];
      float4 B = colqB[P];
      v2f xx = {A.x, A.y}, yy = {A.z, A.w};
      v2f zz = {B.x, B.y}, ss = {B.z, B.w};
#pragma unroll
      for (int i = 0; i < RM; i += 2) {  // 2 rows x 2 cols micro-tile
        v2f v0 = pk_fma(rzp[i], zz, ss);
        v2f v1 = pk_fma(rzp[i + 1], zz, ss);
        v0 = pk_fma(ryp[i], yy, v0);
        v1 = pk_fma(ryp[i + 1], yy, v1);
        v0 = pk_fma(rxp[i], xx, v0);
        v1 = pk_fma(rxp[i + 1], xx, v1);
        rmn[i] = min3f(rmn[i], v0.x, v0.y);          // fwd row-min
        rmn[i + 1] = min3f(rmn[i + 1], v1.x, v1.y);
        v2f cv0 = v0 + sqp[i];                       // full d2 for bwd
        v2f cv1 = v1 + sqp[i + 1];
        cm[q].x = min3f(cm[q].x, cv0.x, cv1.x);      // col-min, 2 rows/inst
        cm[q].y = min3f(cm[q].y, cv0.y, cv1.y);
      }
    }
    // Flush col-mins: wave-internal reduce over the 4 row-subgroups,
    // then LDS atomicMin (on-chip only — R8 lesson).
#pragma unroll
    for (int q = 0; q < QPC; ++q) {
      float a = cm[q].x, b = cm[q].y;
      a = fminf(a, __shfl_xor(a, 16)); a = fminf(a, __shfl_xor(a, 32));
      b = fminf(b, __shfl_xor(b, 16)); b = fminf(b, __shfl_xor(b, 32));
      if (((t >> 4) & 3) == 0) {
        const int P = k * 128 + q * 16 + c;
        atomicMin(&cmb[2 * P], __float_as_uint(fmaxf(a, 0.f)));
        atomicMin(&cmb[2 * P + 1], __float_as_uint(fmaxf(b, 0.f)));
      }
    }
  }

  // Row finish: butterfly over the 16 c-lanes, sqrt, per-wave sum.
  float rsum = 0.f;
#pragma unroll
  for (int i = 0; i < RM; ++i) {
    float a = rmn[i];
    a = fminf(a, __shfl_xor(a, 1));
    a = fminf(a, __shfl_xor(a, 2));
    a = fminf(a, __shfl_xor(a, 4));
    a = fminf(a, __shfl_xor(a, 8));
    rsum += sqrtf(fmaxf(sqp[i].x + a, 0.f));
  }
  float v = (c == 0) ? rsum : 0.f;
  for (int off = 32; off; off >>= 1) v += __shfl_down(v, off);
  if ((t & 63) == 0) wred[t >> 6] = v;
  __syncthreads();

  if (t == 0) {
    float s = 0.f;
#pragma unroll
    for (int w = 0; w < 16; ++w) s += wred[w];
    ws[64 + blockIdx.x] = s;  // complete row contribution of this half
  }
  // Col partial mins (over this half's 512 rows): plain coalesced store.
  float* colpart = ws + 1024;
  colpart[((size_t)half * BK + bk) * NPTS + t] = __uint_as_float(cmb[t]);
}

__global__ __launch_bounds__(256) void chamfer_merge_kernel(
    const float* __restrict__ ws, float* __restrict__ acc, int BK) {
  const int bk = blockIdx.x;
  const int t = threadIdx.x;
  const float* colpart = ws + 1024;
  const float4* c0 = (const float4*)(colpart + (size_t)bk * NPTS);
  const float4* c1 = (const float4*)(colpart + ((size_t)BK + bk) * NPTS);
  float4 a = c0[t], b = c1[t];  // 256 float4 = 1024 cols
  float s = sqrtf(fminf(a.x, b.x)) + sqrtf(fminf(a.y, b.y)) +
            sqrtf(fminf(a.z, b.z)) + sqrtf(fminf(a.w, b.w));
  if (t < 2) s += ws[64 + 2 * bk + t];  // the bk's two row-half sums
  for (int off = 32; off; off >>= 1) s += __shfl_down(s, off);
  __shared__ float wr[4];
  if ((t & 63) == 0) wr[t >> 6] = s;
  __syncthreads();
  if (t == 0) atomicAdd(acc, wr[0] + wr[1] + wr[2] + wr[3]);
}

__global__ void chamfer_scale_kernel(const float* __restrict__ acc,
                                     float* __restrict__ out, float scale) {
  if (threadIdx.x == 0) out[0] = acc[0] * scale;
}

extern "C" void kernel_launch(void* const* d_in, const int* in_sizes, int n_in,
                              void* d_out, int out_size, void* d_ws, size_t ws_size,
                              hipStream_t stream) {
  const float* src = (const float*)d_in[0];  // [B,K,3,M]
  const float* dst = (const float*)d_in[1];  // [B,K,3,N]
  float* out = (float*)d_out;                // scalar f32
  float* ws = (float*)d_ws;

  const int BK = in_sizes[0] / (3 * NPTS);        // 16*8 = 128
  const float scale = 1.0f / (float)(BK * NPTS);  // 1/(B*K*M), M==N

  chamfer_half_kernel<<<dim3(2 * BK), TPB, 0, stream>>>(src, dst, ws, BK);
  chamfer_merge_kernel<<<dim3(BK), 256, 0, stream>>>(ws, ws, BK);
  chamfer_scale_kernel<<<dim3(1), 64, 0, stream>>>(ws, out, scale);
}

// Round 11
// 81.496 us; speedup vs baseline: 2.6596x; 1.0105x over previous
//
#include <hip/hip_runtime.h>

// PartChamferLoss: src/dst [B=16, K=8, 3, 1024] f32 -> scalar f32.
// R11: self-verifying MFMA kernel. Probe MFMAs discover the actual
// operand-pairing and C/D orientation at runtime; the block picks the
// matching extraction path, or a scalar-f32 fallback (always correct).
//   probe0: A=B= per-slot values s -> D == sum(s^2) = 10416 iff A/B slots
//           pair elementwise (rearrangement inequality, exact ints).
//   probe1: A=e_k0, B[k0][j]=1+j -> d[r] = 1+col(lane,r)  (col map).
//   probe2: mirror -> d[r] = 1+row(lane,r)                 (row map).
//   content check: wave0 re-MFMAs tile(0,0) from real fragments, compares
//   sum_r d[r] vs scalar-f32 d2 sums under both candidate reg-orders.
// d2 tile via one mfma_f32_16x16x32_bf16: rank-13 contraction
//   k: 9 split-bf16 cross terms (u=-2p), 2x sq_m*1, 2x 1*sq_n, rest 0.

typedef __attribute__((ext_vector_type(8))) short bf16x8;
typedef __attribute__((ext_vector_type(4))) float f32x4;

#define NPTS 1024
#define TPB 1024

__device__ __forceinline__ ushort bf16h(float f) {  // RNE f32->bf16 bits
  unsigned b = __float_as_uint(f);
  return (ushort)((b + 0x7FFFu + ((b >> 16) & 1u)) >> 16);
}
__device__ __forceinline__ float bf16f(ushort h) {
  return __uint_as_float((unsigned)h << 16);
}
__device__ __forceinline__ f32x4 MFMA(bf16x8 a, bf16x8 b, f32x4 c) {
  return __builtin_amdgcn_mfma_f32_16x16x32_bf16(a, b, c, 0, 0, 0);
}
__device__ __forceinline__ float d2ref_(const float* P, const float* Q,
                                        int i, int j) {
  float dx = P[i] - Q[j];
  float dy = P[NPTS + i] - Q[NPTS + j];
  float dz = P[2 * NPTS + i] - Q[2 * NPTS + j];
  return fmaf(dx, dx, fmaf(dy, dy, dz * dz));
}

__global__ __launch_bounds__(TPB) void chamfer_k1(
    const float* __restrict__ src, const float* __restrict__ dst,
    float* __restrict__ ws, int BK) {
  __shared__ uint4 fragA[512 * 2];   // 16 KB
  __shared__ uint4 fragB[1024 * 2];  // 32 KB
  __shared__ unsigned cmb[NPTS];     // 4 KB col-min combine (uint-ordered)
  __shared__ float wred[16];
  __shared__ float4 rowF[512];       // fallback floats
  __shared__ float4 colF[1024];
  __shared__ int s_mode;

  const int t = threadIdx.x;
  const int lane = t & 63;
  const int m16 = lane & 15;
  const int kb = lane >> 4;
  const int wv = t >> 6;
  const int bk = blockIdx.x >> 1, half = blockIdx.x & 1;
  const float* S = src + (size_t)bk * 3 * NPTS;
  const float* D = dst + (size_t)bk * 3 * NPTS;

  if (blockIdx.x == 0 && t == 0) ws[0] = 0.f;  // init merge accumulator
  cmb[t] = 0x7F800000u;                        // +inf

  // ---- stage bf16 fragments (13-slot contraction operands) ----
  const unsigned ONE = 0x3F80u;  // bf16 1.0
  if (t < 512) {
    const int m = half * 512 + t;
    float x = S[m], y = S[NPTS + m], z = S[2 * NPTS + m];
    float sq = fmaf(x, x, fmaf(y, y, z * z));
    float ux = -2.f * x, uy = -2.f * y, uz = -2.f * z;
    unsigned xh = bf16h(ux), yh = bf16h(uy), zh = bf16h(uz);
    unsigned xl = bf16h(ux - bf16f(xh)), yl = bf16h(uy - bf16f(yh)),
             zl = bf16h(uz - bf16f(zh));
    unsigned sh = bf16h(sq), sl = bf16h(sq - bf16f(sh));
    fragA[t * 2] = make_uint4(xh | (yh << 16), zh | (xh << 16),
                              yh | (zh << 16), xl | (yl << 16));
    fragA[t * 2 + 1] = make_uint4(zl | (sh << 16), sl | (ONE << 16), ONE, 0u);
  }
  {
    float x = D[t], y = D[NPTS + t], z = D[2 * NPTS + t];
    float sq = fmaf(x, x, fmaf(y, y, z * z));
    unsigned xh = bf16h(x), yh = bf16h(y), zh = bf16h(z);
    unsigned xl = bf16h(x - bf16f(xh)), yl = bf16h(y - bf16f(yh)),
             zl = bf16h(z - bf16f(zh));
    unsigned sh = bf16h(sq), sl = bf16h(sq - bf16f(sh));
    fragB[t * 2] = make_uint4(xh | (yh << 16), zh | (xl << 16),
                              yl | (zl << 16), xh | (yh << 16));
    fragB[t * 2 + 1] = make_uint4(zh | (ONE << 16), ONE | (sh << 16), sl, 0u);
  }
  __syncthreads();

  // ---- probes (register-only) ----
  const f32x4 cz = {0.f, 0.f, 0.f, 0.f};
  bf16x8 z8;
#pragma unroll
  for (int j = 0; j < 8; ++j) z8[j] = 0;
  bf16x8 pa = z8, pb = z8;
#pragma unroll
  for (int j = 0; j < 8; ++j) pa[j] = (short)bf16h((float)(kb * 8 + j));
  f32x4 q0 = MFMA(pa, pa, cz);
  int ok0 = (q0[0] == 10416.f) && (q0[1] == 10416.f) &&
            (q0[2] == 10416.f) && (q0[3] == 10416.f);
  pa = z8; pb = z8;
  if (kb == 0) { pa[0] = (short)bf16h(1.f); pb[0] = (short)bf16h((float)(1 + m16)); }
  f32x4 q1 = MFMA(pa, pb, cz);
  pa = z8; pb = z8;
  if (kb == 0) { pa[0] = (short)bf16h((float)(1 + m16)); pb[0] = (short)bf16h(1.f); }
  f32x4 q2 = MFMA(pa, pb, cz);

  int colm = 1, rowm = 1, gokv = 1;
  int gofs[4];
#pragma unroll
  for (int r = 0; r < 4; ++r) {
    colm &= (q1[r] == (float)(1 + m16));
    rowm &= (q2[r] == (float)(1 + m16));
    gofs[r] = (int)q1[r] - 1;  // discovered col label (path B)
    gokv &= (gofs[r] >= 0 && gofs[r] < 16);
  }
  colm = __all(colm && ok0);
  rowm = __all(rowm && ok0);
  gokv = __all(gokv);

  if (wv == 0) {
    int mode = (colm && !rowm) ? 0 : ((rowm && !colm && gokv) ? 1 : 2);
    if (mode != 2) {  // content spot-check on real fragments, tile (0,0)
      bf16x8 a0 = *(const bf16x8*)&fragA[(m16 * 2) + (kb & 1)];
      if (kb >= 2) a0 = z8;
      bf16x8 b0 = *(const bf16x8*)&fragB[(m16 * 2) + (kb & 1)];
      f32x4 dchk = MFMA(a0, b0, cz);
      float s4 = dchk[0] + dchk[1] + dchk[2] + dchk[3];
      float refg = 0.f, refr = 0.f;
#pragma unroll
      for (int r = 0; r < 4; ++r) {
        int ig = 4 * kb + r, ir = kb + 4 * r;  // candidate reg-orders
        refg += d2ref_(S, D, half * 512 + (mode == 0 ? ig : m16),
                       (mode == 0 ? m16 : ig));
        refr += d2ref_(S, D, half * 512 + (mode == 0 ? ir : m16),
                       (mode == 0 ? m16 : ir));
      }
      int cg = fabsf(s4 - refg) <= 0.1f + 5e-3f * fabsf(refg);
      int cr = fabsf(s4 - refr) <= 0.1f + 5e-3f * fabsf(refr);
      if (!__all(cg) && !__all(cr)) mode = 2;
    }
    if (lane == 0) s_mode = mode;
  }
  __syncthreads();
  const int mode = s_mode;

  float rs = 0.f;  // this thread's forward (row) contribution

  if (mode == 0 || mode == 1) {
    bf16x8 a0 = *(const bf16x8*)&fragA[(((wv * 2 + 0) * 16 + m16) * 2) + (kb & 1)];
    bf16x8 a1 = *(const bf16x8*)&fragA[(((wv * 2 + 1) * 16 + m16) * 2) + (kb & 1)];
    if (kb >= 2) { a0 = z8; a1 = z8; }
    float r0[4], r1[4];
#pragma unroll
    for (int r = 0; r < 4; ++r) { r0[r] = 3.4e38f; r1[r] = 3.4e38f; }

    if (mode == 0) {
      // H=A (m89): d[r] = D[g(kb,r)][m16]
      for (int ct = 0; ct < 64; ++ct) {
        bf16x8 b = *(const bf16x8*)&fragB[((ct * 16 + m16) * 2) + (kb & 1)];
        f32x4 d0 = MFMA(a0, b, cz);
        f32x4 d1 = MFMA(a1, b, cz);
#pragma unroll
        for (int r = 0; r < 4; ++r) {
          r0[r] = fminf(r0[r], d0[r]);
          r1[r] = fminf(r1[r], d1[r]);
        }
        float c = fminf(fminf(d0[0], d0[1]), fminf(d0[2], d0[3]));
        c = fminf(c, fminf(fminf(d1[0], d1[1]), fminf(d1[2], d1[3])));
        c = fminf(c, __shfl_xor(c, 16));
        c = fminf(c, __shfl_xor(c, 32));
        if (kb == 0)
          atomicMin(&cmb[ct * 16 + m16], __float_as_uint(fmaxf(c, 0.f)));
      }
#pragma unroll
      for (int r = 0; r < 4; ++r) {
        float v = r0[r];
        v = fminf(v, __shfl_xor(v, 1));
        v = fminf(v, __shfl_xor(v, 2));
        v = fminf(v, __shfl_xor(v, 4));
        v = fminf(v, __shfl_xor(v, 8));
        rs += sqrtf(fmaxf(v, 0.f));
        v = r1[r];
        v = fminf(v, __shfl_xor(v, 1));
        v = fminf(v, __shfl_xor(v, 2));
        v = fminf(v, __shfl_xor(v, 4));
        v = fminf(v, __shfl_xor(v, 8));
        rs += sqrtf(fmaxf(v, 0.f));
      }
      rs = (m16 == 0) ? rs : 0.f;
    } else {
      // H=B (transposed): d[r] = D[m16][g(kb,r)], labels from gofs[]
      for (int ct = 0; ct < 64; ++ct) {
        bf16x8 b = *(const bf16x8*)&fragB[((ct * 16 + m16) * 2) + (kb & 1)];
        f32x4 d0 = MFMA(a0, b, cz);
        f32x4 d1 = MFMA(a1, b, cz);
#pragma unroll
        for (int r = 0; r < 4; ++r) {
          r0[r] = fminf(r0[r], d0[r]);
          r1[r] = fminf(r1[r], d1[r]);
          float c = fminf(d0[r], d1[r]);  // min over both row-tiles
          c = fminf(c, __shfl_xor(c, 1));
          c = fminf(c, __shfl_xor(c, 2));
          c = fminf(c, __shfl_xor(c, 4));
          c = fminf(c, __shfl_xor(c, 8));
          if (m16 == 0)
            atomicMin(&cmb[ct * 16 + gofs[r]], __float_as_uint(fmaxf(c, 0.f)));
        }
      }
      float vA = fminf(fminf(r0[0], r0[1]), fminf(r0[2], r0[3]));
      vA = fminf(vA, __shfl_xor(vA, 16));
      vA = fminf(vA, __shfl_xor(vA, 32));
      float vB = fminf(fminf(r1[0], r1[1]), fminf(r1[2], r1[3]));
      vB = fminf(vB, __shfl_xor(vB, 16));
      vB = fminf(vB, __shfl_xor(vB, 32));
      rs = sqrtf(fmaxf(vA, 0.f)) + sqrtf(fmaxf(vB, 0.f));
      rs = (kb == 0) ? rs : 0.f;
    }
  } else {
    // ---- scalar f32 fallback (always correct) ----
    if (t < 512) {
      int m = half * 512 + t;
      rowF[t] = make_float4(S[m], S[NPTS + m], S[2 * NPTS + m], 0.f);
    }
    colF[t] = make_float4(D[t], D[NPTS + t], D[2 * NPTS + t], 0.f);
    __syncthreads();
    if (t < 512) {
      float4 p = rowF[t];
      float mn = 3.4e38f;
      for (int n = 0; n < NPTS; ++n) {
        float4 q = colF[n];
        float dx = p.x - q.x, dy = p.y - q.y, dz = p.z - q.z;
        mn = fminf(mn, fmaf(dx, dx, fmaf(dy, dy, dz * dz)));
      }
      rs = sqrtf(mn);
    }
    {
      float4 q = colF[t];
      float mc = 3.4e38f;
      for (int m = 0; m < 512; ++m) {
        float4 p = rowF[m];
        float dx = p.x - q.x, dy = p.y - q.y, dz = p.z - q.z;
        mc = fminf(mc, fmaf(dx, dx, fmaf(dy, dy, dz * dz)));
      }
      cmb[t] = __float_as_uint(mc);  // own slot, no race
    }
  }

  // ---- common epilogue ----
  __syncthreads();  // cmb atomics complete
  float v = rs;
  for (int off = 32; off; off >>= 1) v += __shfl_down(v, off);
  if (lane == 0) wred[wv] = v;
  __syncthreads();
  if (t == 0) {
    float s = 0.f;
#pragma unroll
    for (int w = 0; w < 16; ++w) s += wred[w];
    ws[64 + blockIdx.x] = s;
  }
  float* colpart = ws + 1024;
  colpart[((size_t)half * BK + bk) * NPTS + t] = __uint_as_float(cmb[t]);
}

__global__ __launch_bounds__(256) void chamfer_merge_kernel(
    const float* __restrict__ ws, float* __restrict__ acc, int BK) {
  const int bk = blockIdx.x;
  const int t = threadIdx.x;
  const float* colpart = ws + 1024;
  const float4* c0 = (const float4*)(colpart + (size_t)bk * NPTS);
  const float4* c1 = (const float4*)(colpart + ((size_t)BK + bk) * NPTS);
  float4 a = c0[t], b = c1[t];
  float s = sqrtf(fminf(a.x, b.x)) + sqrtf(fminf(a.y, b.y)) +
            sqrtf(fminf(a.z, b.z)) + sqrtf(fminf(a.w, b.w));
  if (t < 2) s += ws[64 + 2 * bk + t];
  for (int off = 32; off; off >>= 1) s += __shfl_down(s, off);
  __shared__ float wr[4];
  if ((t & 63) == 0) wr[t >> 6] = s;
  __syncthreads();
  if (t == 0) atomicAdd(acc, wr[0] + wr[1] + wr[2] + wr[3]);
}

__global__ void chamfer_scale_kernel(const float* __restrict__ acc,
                                     float* __restrict__ out, float scale) {
  if (threadIdx.x == 0) out[0] = acc[0] * scale;
}

extern "C" void kernel_launch(void* const* d_in, const int* in_sizes, int n_in,
                              void* d_out, int out_size, void* d_ws, size_t ws_size,
                              hipStream_t stream) {
  const float* src = (const float*)d_in[0];  // [B,K,3,M]
  const float* dst = (const float*)d_in[1];  // [B,K,3,N]
  float* out = (float*)d_out;                // scalar f32
  float* ws = (float*)d_ws;

  const int BK = in_sizes[0] / (3 * NPTS);        // 16*8 = 128
  const float scale = 1.0f / (float)(BK * NPTS);  // 1/(B*K*M), M==N

  chamfer_k1<<<dim3(2 * BK), TPB, 0, stream>>>(src, dst, ws, BK);
  chamfer_merge_kernel<<<dim3(BK), 256, 0, stream>>>(ws, ws, BK);
  chamfer_scale_kernel<<<dim3(1), 64, 0, stream>>>(ws, out, scale);
}